// Round 1
// baseline (3587.568 us; speedup 1.0000x reference)
//
#include <hip/hip_runtime.h>
#include <cstdint>
#include <cstddef>

static constexpr int Nn = 8192;   // rows of X
static constexpr int Mm = 8192;   // rows of Y
static constexpr int Kd = 256;    // feature dim
static constexpr float LAM_F   = 10.0f;
static constexpr float INV_N_F = 1.0f / 8192.0f;

typedef _Float16 h16;
typedef _Float16 h16x4 __attribute__((ext_vector_type(4)));

// ---------- load/store helpers (overloaded on storage type) ----------
__device__ __forceinline__ void load8(const h16* p, float* o) {
  uint4 q = *(const uint4*)p;               // 16B aligned in fast path
  const h16* h = (const h16*)&q;
#pragma unroll
  for (int i = 0; i < 8; ++i) o[i] = (float)h[i];
}
__device__ __forceinline__ void load8(const float* p, float* o) {
#pragma unroll
  for (int i = 0; i < 8; ++i) o[i] = p[i];  // fallback path (misaligned base ok)
}
__device__ __forceinline__ void store4e(h16* p, float a, float b, float c, float d) {
  h16x4 h; h[0] = (h16)a; h[1] = (h16)b; h[2] = (h16)c; h[3] = (h16)d;
  *(h16x4*)p = h;                           // 8B aligned
}
__device__ __forceinline__ void store4e(float* p, float a, float b, float c, float d) {
  p[0] = a; p[1] = b; p[2] = c; p[3] = d;
}

// ---------- setup: row norms, u=1, cost=0 ----------
__global__ __launch_bounds__(256) void setup_kernel(
    const float* __restrict__ X, const float* __restrict__ Y,
    float* __restrict__ x2, float* __restrict__ y2,
    float* __restrict__ u, float* __restrict__ cost) {
  const int gid  = blockIdx.x * blockDim.x + threadIdx.x;
  const int wid  = gid >> 6;          // 0..16383 : one wave per row
  const int lane = threadIdx.x & 63;
  const bool isX = wid < Nn;
  const int row  = isX ? wid : wid - Nn;
  const float4* rp = (const float4*)((isX ? X : Y) + (size_t)row * Kd);
  float4 q = rp[lane];                // 64 lanes x float4 = 256 floats
  float s = q.x*q.x + q.y*q.y + q.z*q.z + q.w*q.w;
#pragma unroll
  for (int o = 32; o > 0; o >>= 1) s += __shfl_down(s, o);
  if (lane == 0) { if (isX) x2[row] = s; else y2[row] = s; }
  if (gid < Mm) u[gid] = 1.0f;        // g0 = 0  ->  u0 = 1
  if (gid == 0) cost[0] = 0.0f;
}

// ---------- build K = exp(-C/LAM): fp32 vector GEMM, 64x64 tile, 4x4/thread ----------
template <typename ET>
__global__ __launch_bounds__(256) void build_e_kernel(
    const float* __restrict__ X, const float* __restrict__ Y,
    const float* __restrict__ x2, const float* __restrict__ y2,
    ET* __restrict__ E) {
  // [k][i] layout, pad 66: transposed LDS writes stride 66 -> 2-way bank alias (free),
  // compute reads merge to b64 (8B aligned), read banks conflict-free / 2-way.
  __shared__ float As[64][66];
  __shared__ float Bs[64][66];
  const int tid = threadIdx.x;
  const int tx = tid & 15;       // j micro-tile
  const int ty = tid >> 4;       // i micro-tile
  const int i0 = blockIdx.y * 64;
  const int j0 = blockIdx.x * 64;
  float acc[4][4] = {};
  for (int k0 = 0; k0 < Kd; k0 += 64) {
    __syncthreads();
#pragma unroll
    for (int rep = 0; rep < 16; ++rep) {
      const int e = rep * 256 + tid;         // 0..4095
      const int k = e & 63, i = e >> 6;      // consecutive tid -> consecutive k (coalesced)
      As[k][i] = X[(size_t)(i0 + i) * Kd + k0 + k];
      Bs[k][i] = Y[(size_t)(j0 + i) * Kd + k0 + k];
    }
    __syncthreads();
    for (int k = 0; k < 64; ++k) {
      float a0 = As[k][ty*4+0], a1 = As[k][ty*4+1], a2 = As[k][ty*4+2], a3 = As[k][ty*4+3];
      float b0 = Bs[k][tx*4+0], b1 = Bs[k][tx*4+1], b2 = Bs[k][tx*4+2], b3 = Bs[k][tx*4+3];
      acc[0][0] += a0*b0; acc[0][1] += a0*b1; acc[0][2] += a0*b2; acc[0][3] += a0*b3;
      acc[1][0] += a1*b0; acc[1][1] += a1*b1; acc[1][2] += a1*b2; acc[1][3] += a1*b3;
      acc[2][0] += a2*b0; acc[2][1] += a2*b1; acc[2][2] += a2*b2; acc[2][3] += a2*b3;
      acc[3][0] += a3*b0; acc[3][1] += a3*b1; acc[3][2] += a3*b2; acc[3][3] += a3*b3;
    }
  }
  float xx[4], yy[4];
#pragma unroll
  for (int d = 0; d < 4; ++d) { xx[d] = x2[i0 + ty*4 + d]; yy[d] = y2[j0 + tx*4 + d]; }
#pragma unroll
  for (int di = 0; di < 4; ++di) {
    float e4[4];
#pragma unroll
    for (int dj = 0; dj < 4; ++dj) {
      float sq = xx[di] + yy[dj] - 2.0f * acc[di][dj];
      float c  = sqrtf(fmaxf(sq, 0.0f) + 1e-6f);
      e4[dj] = __expf(-c * 0.1f);
    }
    store4e(&E[(size_t)(i0 + ty*4 + di) * Mm + j0 + tx*4], e4[0], e4[1], e4[2], e4[3]);
  }
}

// ---------- row pass: v_i = (1/n) / sum_j K_ij u_j  (one wave per row) ----------
template <typename ET>
__global__ __launch_bounds__(256) void row_pass_kernel(
    const ET* __restrict__ E, const float* __restrict__ u, float* __restrict__ v) {
  const int wid  = (blockIdx.x * blockDim.x + threadIdx.x) >> 6;
  const int lane = threadIdx.x & 63;
  const ET* row = E + (size_t)wid * Mm;
  float s = 0.0f;
#pragma unroll 4
  for (int g = 0; g < 16; ++g) {
    const int j8 = (g * 64 + lane) * 8;
    float ev[8]; load8(row + j8, ev);
    const float4 u0 = *(const float4*)(u + j8);
    const float4 u1 = *(const float4*)(u + j8 + 4);
    s += ev[0]*u0.x + ev[1]*u0.y + ev[2]*u0.z + ev[3]*u0.w;
    s += ev[4]*u1.x + ev[5]*u1.y + ev[6]*u1.z + ev[7]*u1.w;
  }
#pragma unroll
  for (int o = 32; o > 0; o >>= 1) s += __shfl_down(s, o);
  if (lane == 0) v[wid] = INV_N_F / s;
}

// ---------- col pass partials: part[chunk][j] = sum_{i in chunk} K_ij v_i ----------
template <typename ET>
__global__ __launch_bounds__(256) void col_pass_kernel(
    const ET* __restrict__ E, const float* __restrict__ v, float* __restrict__ part) {
  const int c0 = blockIdx.x * 2048 + threadIdx.x * 8;   // 8 consecutive cols / thread
  const int r0 = blockIdx.y * 64;                       // 64-row chunk
  float acc[8] = {};
#pragma unroll 4
  for (int r = r0; r < r0 + 64; ++r) {
    const float vr = v[r];                              // block-uniform -> s_load
    float ev[8]; load8(E + (size_t)r * Mm + c0, ev);
#pragma unroll
    for (int c = 0; c < 8; ++c) acc[c] += ev[c] * vr;
  }
  float* dst = part + (size_t)blockIdx.y * Mm + c0;
  *(float4*)dst       = make_float4(acc[0], acc[1], acc[2], acc[3]);
  *((float4*)dst + 1) = make_float4(acc[4], acc[5], acc[6], acc[7]);
}

// ---------- combine: u_j = (1/m) / sum_chunks part ----------
__global__ __launch_bounds__(256) void combine_kernel(
    const float* __restrict__ part, float* __restrict__ u) {
  const int j = blockIdx.x * blockDim.x + threadIdx.x;
  float t = 0.0f;
#pragma unroll 8
  for (int c = 0; c < 128; ++c) t += part[(size_t)c * Mm + j];
  u[j] = INV_N_F / t;
}

// ---------- final: pi = v_i K_ij u_j ; cost = sum pi * (-LAM log K) ----------
template <typename ET>
__global__ __launch_bounds__(256) void final_pass_kernel(
    const ET* E, const float* __restrict__ v, const float* __restrict__ u,
    float* pi, float* cost) {            // E/pi may alias (fallback) -> no restrict
  const int wid  = (blockIdx.x * blockDim.x + threadIdx.x) >> 6;
  const int lane = threadIdx.x & 63;
  const ET* row = E + (size_t)wid * Mm;
  float* prow = pi + (size_t)wid * Mm;
  const float vi = v[wid];
  float csum = 0.0f;
  for (int g = 0; g < 16; ++g) {
    const int j8 = (g * 64 + lane) * 8;
    float ev[8]; load8(row + j8, ev);
#pragma unroll
    for (int c = 0; c < 8; ++c) {
      const float uu  = u[j8 + c];
      const float p   = vi * ev[c] * uu;
      const float Cij = -LAM_F * __logf(ev[c]);
      prow[j8 + c] = p;                 // scalar stores: pi base (out+1) is 4B-aligned only
      csum += p * Cij;
    }
  }
#pragma unroll
  for (int o = 32; o > 0; o >>= 1) csum += __shfl_down(csum, o);
  if (lane == 0) atomicAdd(cost, csum);
}

// ---------- host ----------
extern "C" void kernel_launch(void* const* d_in, const int* in_sizes, int n_in,
                              void* d_out, int out_size, void* d_ws, size_t ws_size,
                              hipStream_t stream) {
  const float* X = (const float*)d_in[0];
  const float* Y = (const float*)d_in[1];
  float* out  = (float*)d_out;
  float* cost = out;
  float* pi   = out + 1;

  char*  ws   = (char*)d_ws;
  float* x2   = (float*)ws;
  float* y2   = x2 + Nn;
  float* u    = y2 + Mm;
  float* v    = u + Mm;
  float* part = v + Nn;                                   // 128 x 8192 f32 = 4 MB
  const size_t small_bytes = (size_t)(4 * 8192 + 128 * 8192) * sizeof(float);
  const size_t e_off = (small_bytes + 255) & ~(size_t)255;
  const bool fast = ws_size >= e_off + (size_t)Nn * Mm * sizeof(h16) + 256;

  setup_kernel<<<4096, 256, 0, stream>>>(X, Y, x2, y2, u, cost);

  if (fast) {
    h16* E = (h16*)(ws + e_off);                          // fp16 K in workspace (128 MB, L3-resident)
    build_e_kernel<h16><<<dim3(128, 128), 256, 0, stream>>>(X, Y, x2, y2, E);
    for (int it = 0; it < 50; ++it) {
      row_pass_kernel<h16><<<2048, 256, 0, stream>>>(E, u, v);
      col_pass_kernel<h16><<<dim3(4, 128), 256, 0, stream>>>(E, v, part);
      combine_kernel<<<32, 256, 0, stream>>>(part, u);
    }
    final_pass_kernel<h16><<<2048, 256, 0, stream>>>(E, v, u, pi, cost);
  } else {
    float* E = pi;                                        // fallback: fp32 K parked in pi slot
    build_e_kernel<float><<<dim3(128, 128), 256, 0, stream>>>(X, Y, x2, y2, E);
    for (int it = 0; it < 50; ++it) {
      row_pass_kernel<float><<<2048, 256, 0, stream>>>(E, u, v);
      col_pass_kernel<float><<<dim3(4, 128), 256, 0, stream>>>(E, v, part);
      combine_kernel<<<32, 256, 0, stream>>>(part, u);
    }
    final_pass_kernel<float><<<2048, 256, 0, stream>>>(E, v, u, pi, cost);  // in-place
  }
}

// Round 3
// 2980.658 us; speedup vs baseline: 1.2036x; 1.2036x over previous
//
#include <hip/hip_runtime.h>
#include <cstdint>
#include <cstddef>

static constexpr int Nn = 8192;   // rows of X
static constexpr int Mm = 8192;   // rows of Y
static constexpr int Kd = 256;    // feature dim
static constexpr float LAM_F   = 10.0f;
static constexpr float INV_N_F = 1.0f / 8192.0f;

typedef _Float16 h16;
typedef _Float16 h16x4 __attribute__((ext_vector_type(4)));
typedef _Float16 f16x8 __attribute__((ext_vector_type(8)));
typedef float    f32x16 __attribute__((ext_vector_type(16)));

// ---------- load/store helpers (overloaded on storage type) ----------
__device__ __forceinline__ void load8(const h16* p, float* o) {
  uint4 q = *(const uint4*)p;               // 16B aligned in fast path
  const h16* h = (const h16*)&q;
#pragma unroll
  for (int i = 0; i < 8; ++i) o[i] = (float)h[i];
}
__device__ __forceinline__ void load8(const float* p, float* o) {
#pragma unroll
  for (int i = 0; i < 8; ++i) o[i] = p[i];  // fallback path
}
__device__ __forceinline__ void store4e(float* p, float a, float b, float c, float d) {
  p[0] = a; p[1] = b; p[2] = c; p[3] = d;
}

// ---------- setup: row norms, u=1, cost=0, fp16 copies of X,Y ----------
__global__ __launch_bounds__(256) void setup_kernel(
    const float* __restrict__ X, const float* __restrict__ Y,
    float* __restrict__ x2, float* __restrict__ y2,
    float* __restrict__ u, float* __restrict__ cost,
    h16* __restrict__ Xh, h16* __restrict__ Yh) {
  const int gid  = blockIdx.x * blockDim.x + threadIdx.x;
  const int wid  = gid >> 6;          // 0..16383 : one wave per row
  const int lane = threadIdx.x & 63;
  const bool isX = wid < Nn;
  const int row  = isX ? wid : wid - Nn;
  const float4* rp = (const float4*)((isX ? X : Y) + (size_t)row * Kd);
  float4 q = rp[lane];                // 64 lanes x float4 = 256 floats
  // fp16 copy for the MFMA cost-matrix build
  h16x4 hq; hq[0] = (h16)q.x; hq[1] = (h16)q.y; hq[2] = (h16)q.z; hq[3] = (h16)q.w;
  *(h16x4*)((isX ? Xh : Yh) + (size_t)row * Kd + lane * 4) = hq;
  float s = q.x*q.x + q.y*q.y + q.z*q.z + q.w*q.w;
#pragma unroll
  for (int o = 32; o > 0; o >>= 1) s += __shfl_down(s, o);
  if (lane == 0) { if (isX) x2[row] = s; else y2[row] = s; }
  if (gid < Mm) u[gid] = 1.0f;        // g0 = 0  ->  u0 = 1
  if (gid == 0) cost[0] = 0.0f;
}

// ---------- build K = exp(-C/LAM) via MFMA f16, 128x128 tile ----------
// LDS holds A/B pre-swizzled in 32x32x16 fragment order:
//   chunk index ((mt*4 + s)*64 + m + 32*half), each chunk = 8 halves (16 B)
//   -> ds_read_b128 at lane*16 + imm, conflict-free by construction.
__global__ __launch_bounds__(256) void build_e_mfma(
    const h16* __restrict__ Xh, const h16* __restrict__ Yh,
    const float* __restrict__ x2, const float* __restrict__ y2,
    h16* __restrict__ E) {
  __shared__ h16 smem[16384];         // 32 KB: A[0..8191], B[8192..16383]; epilogue reuses as 128x128 tile
  __shared__ float x2s[128], y2s[128];
  const int tid = threadIdx.x;
  const int i0 = blockIdx.y * 128, j0 = blockIdx.x * 128;
  if (tid < 128) x2s[tid] = x2[i0 + tid];
  else           y2s[tid - 128] = y2[j0 + tid - 128];

  f32x16 acc[2][2];
#pragma unroll
  for (int a = 0; a < 2; ++a)
#pragma unroll
    for (int b = 0; b < 2; ++b)
#pragma unroll
      for (int r = 0; r < 16; ++r) acc[a][b][r] = 0.0f;

  const int w = tid >> 6, lane = tid & 63;
  const int mt0 = (w >> 1) * 2, nt0 = (w & 1) * 2;   // wave quadrant: 2 m-tiles x 2 n-tiles of 32

  for (int kc = 0; kc < 4; ++kc) {                   // K = 256 in 4 chunks of 64
    __syncthreads();
#pragma unroll
    for (int p = 0; p < 4; ++p) {                    // stage 128 rows x 64 k (A and B)
      const int c  = p * 256 + tid;                  // 1024 16B-chunks each (8 chunks/row of 64 k)
      const int r  = c >> 3, k8 = c & 7;
      const int mt = r >> 5, m = r & 31, s = k8 >> 1, hf = k8 & 1;
      const int dst = ((mt * 4 + s) * 64 + m + 32 * hf) * 8;
      *(uint4*)(smem + dst)        = *(const uint4*)(Xh + (size_t)(i0 + r) * Kd + kc * 64 + k8 * 8);
      *(uint4*)(smem + 8192 + dst) = *(const uint4*)(Yh + (size_t)(j0 + r) * Kd + kc * 64 + k8 * 8);
    }
    __syncthreads();
#pragma unroll
    for (int s = 0; s < 4; ++s) {                    // 4 k-steps of 16
      f16x8 a0 = *(const f16x8*)(smem + (((mt0    ) * 4 + s) * 64 + lane) * 8);
      f16x8 a1 = *(const f16x8*)(smem + (((mt0 + 1) * 4 + s) * 64 + lane) * 8);
      f16x8 b0 = *(const f16x8*)(smem + 8192 + (((nt0    ) * 4 + s) * 64 + lane) * 8);
      f16x8 b1 = *(const f16x8*)(smem + 8192 + (((nt0 + 1) * 4 + s) * 64 + lane) * 8);
      acc[0][0] = __builtin_amdgcn_mfma_f32_32x32x16_f16(a0, b0, acc[0][0], 0, 0, 0);
      acc[0][1] = __builtin_amdgcn_mfma_f32_32x32x16_f16(a0, b1, acc[0][1], 0, 0, 0);
      acc[1][0] = __builtin_amdgcn_mfma_f32_32x32x16_f16(a1, b0, acc[1][0], 0, 0, 0);
      acc[1][1] = __builtin_amdgcn_mfma_f32_32x32x16_f16(a1, b1, acc[1][1], 0, 0, 0);
    }
  }

  __syncthreads();                                   // all waves done reading A/B
  const int mq = (w >> 1) * 64, nq = (w & 1) * 64;
#pragma unroll
  for (int ti = 0; ti < 2; ++ti)
#pragma unroll
    for (int tj = 0; tj < 2; ++tj) {
      const int colb = nq + tj * 32 + (lane & 31);
      const float yv = y2s[colb];
#pragma unroll
      for (int r = 0; r < 16; ++r) {
        // 32x32 C/D layout: col = lane&31, row = (r&3) + 8*(r>>2) + 4*(lane>>5)
        const int rowb = mq + ti * 32 + (r & 3) + 8 * (r >> 2) + 4 * (lane >> 5);
        float sq = x2s[rowb] + yv - 2.0f * acc[ti][tj][r];
        float cc = sqrtf(fmaxf(sq, 0.0f) + 1e-6f);
        smem[rowb * 128 + colb] = (h16)__expf(-0.1f * cc);
      }
    }
  __syncthreads();
#pragma unroll
  for (int p = 0; p < 8; ++p) {                      // coalesced 16B stores of the 128x128 tile
    const int c = p * 256 + tid;                     // 2048 chunks = 128 rows x 16 chunks
    const int r = c >> 4, k16 = c & 15;              // FIXED: 16 chunks per 128-col row (was >>3/&7)
    *(uint4*)(E + (size_t)(i0 + r) * Mm + j0 + k16 * 8) = *(const uint4*)(smem + r * 128 + k16 * 8);
  }
}

// ---------- fallback fp32 build (ws too small for fp16 E) ----------
template <typename ET>
__global__ __launch_bounds__(256) void build_e_f32(
    const float* __restrict__ X, const float* __restrict__ Y,
    const float* __restrict__ x2, const float* __restrict__ y2,
    ET* __restrict__ E) {
  __shared__ float As[64][66];
  __shared__ float Bs[64][66];
  const int tid = threadIdx.x;
  const int tx = tid & 15;
  const int ty = tid >> 4;
  const int i0 = blockIdx.y * 64;
  const int j0 = blockIdx.x * 64;
  float acc[4][4] = {};
  for (int k0 = 0; k0 < Kd; k0 += 64) {
    __syncthreads();
#pragma unroll
    for (int rep = 0; rep < 16; ++rep) {
      const int e = rep * 256 + tid;
      const int k = e & 63, i = e >> 6;
      As[k][i] = X[(size_t)(i0 + i) * Kd + k0 + k];
      Bs[k][i] = Y[(size_t)(j0 + i) * Kd + k0 + k];
    }
    __syncthreads();
    for (int k = 0; k < 64; ++k) {
      float a0 = As[k][ty*4+0], a1 = As[k][ty*4+1], a2 = As[k][ty*4+2], a3 = As[k][ty*4+3];
      float b0 = Bs[k][tx*4+0], b1 = Bs[k][tx*4+1], b2 = Bs[k][tx*4+2], b3 = Bs[k][tx*4+3];
      acc[0][0] += a0*b0; acc[0][1] += a0*b1; acc[0][2] += a0*b2; acc[0][3] += a0*b3;
      acc[1][0] += a1*b0; acc[1][1] += a1*b1; acc[1][2] += a1*b2; acc[1][3] += a1*b3;
      acc[2][0] += a2*b0; acc[2][1] += a2*b1; acc[2][2] += a2*b2; acc[2][3] += a2*b3;
      acc[3][0] += a3*b0; acc[3][1] += a3*b1; acc[3][2] += a3*b2; acc[3][3] += a3*b3;
    }
  }
  float xx[4], yy[4];
#pragma unroll
  for (int d = 0; d < 4; ++d) { xx[d] = x2[i0 + ty*4 + d]; yy[d] = y2[j0 + tx*4 + d]; }
#pragma unroll
  for (int di = 0; di < 4; ++di) {
    float e4[4];
#pragma unroll
    for (int dj = 0; dj < 4; ++dj) {
      float sq = xx[di] + yy[dj] - 2.0f * acc[di][dj];
      float c  = sqrtf(fmaxf(sq, 0.0f) + 1e-6f);
      e4[dj] = __expf(-c * 0.1f);
    }
    store4e(&E[(size_t)(i0 + ty*4 + di) * Mm + j0 + tx*4], e4[0], e4[1], e4[2], e4[3]);
  }
}

// ---------- row pass: v_i = (1/n) / sum_j K_ij u_j  (one wave per row) ----------
template <typename ET>
__global__ __launch_bounds__(256) void row_pass_kernel(
    const ET* __restrict__ E, const float* __restrict__ u, float* __restrict__ v) {
  const int wid  = (blockIdx.x * blockDim.x + threadIdx.x) >> 6;
  const int lane = threadIdx.x & 63;
  const ET* row = E + (size_t)wid * Mm;
  float s = 0.0f;
#pragma unroll 4
  for (int g = 0; g < 16; ++g) {
    const int j8 = (g * 64 + lane) * 8;
    float ev[8]; load8(row + j8, ev);
    const float4 u0 = *(const float4*)(u + j8);
    const float4 u1 = *(const float4*)(u + j8 + 4);
    s += ev[0]*u0.x + ev[1]*u0.y + ev[2]*u0.z + ev[3]*u0.w;
    s += ev[4]*u1.x + ev[5]*u1.y + ev[6]*u1.z + ev[7]*u1.w;
  }
#pragma unroll
  for (int o = 32; o > 0; o >>= 1) s += __shfl_down(s, o);
  if (lane == 0) v[wid] = INV_N_F / s;
}

// ---------- col pass partials: part[chunk][j] = sum_{i in chunk} K_ij v_i ----------
template <typename ET>
__global__ __launch_bounds__(256) void col_pass_kernel(
    const ET* __restrict__ E, const float* __restrict__ v, float* __restrict__ part) {
  const int c0 = blockIdx.x * 2048 + threadIdx.x * 8;
  const int r0 = blockIdx.y * 64;
  float acc[8] = {};
#pragma unroll 4
  for (int r = r0; r < r0 + 64; ++r) {
    const float vr = v[r];
    float ev[8]; load8(E + (size_t)r * Mm + c0, ev);
#pragma unroll
    for (int c = 0; c < 8; ++c) acc[c] += ev[c] * vr;
  }
  float* dst = part + (size_t)blockIdx.y * Mm + c0;
  *(float4*)dst       = make_float4(acc[0], acc[1], acc[2], acc[3]);
  *((float4*)dst + 1) = make_float4(acc[4], acc[5], acc[6], acc[7]);
}

// ---------- combine: u_j = (1/m) / sum_chunks part ----------
__global__ __launch_bounds__(256) void combine_kernel(
    const float* __restrict__ part, float* __restrict__ u) {
  const int j = blockIdx.x * blockDim.x + threadIdx.x;
  float t = 0.0f;
#pragma unroll 8
  for (int c = 0; c < 128; ++c) t += part[(size_t)c * Mm + j];
  u[j] = INV_N_F / t;
}

// ---------- final: pi = v_i K_ij u_j ; cost = sum pi * (-LAM log K) ----------
template <typename ET>
__global__ __launch_bounds__(256) void final_pass_kernel(
    const ET* E, const float* __restrict__ v, const float* __restrict__ u,
    float* pi, float* cost) {            // E/pi may alias (fallback) -> no restrict
  const int wid  = (blockIdx.x * blockDim.x + threadIdx.x) >> 6;
  const int lane = threadIdx.x & 63;
  const ET* row = E + (size_t)wid * Mm;
  float* prow = pi + (size_t)wid * Mm;
  const float vi = v[wid];
  float csum = 0.0f;
  for (int g = 0; g < 16; ++g) {
    const int j8 = (g * 64 + lane) * 8;
    float ev[8]; load8(row + j8, ev);
#pragma unroll
    for (int c = 0; c < 8; ++c) {
      const float uu  = u[j8 + c];
      const float p   = vi * ev[c] * uu;
      const float Cij = -LAM_F * __logf(ev[c]);
      prow[j8 + c] = p;
      csum += p * Cij;
    }
  }
#pragma unroll
  for (int o = 32; o > 0; o >>= 1) csum += __shfl_down(csum, o);
  if (lane == 0) atomicAdd(cost, csum);
}

// ---------- host ----------
extern "C" void kernel_launch(void* const* d_in, const int* in_sizes, int n_in,
                              void* d_out, int out_size, void* d_ws, size_t ws_size,
                              hipStream_t stream) {
  const float* X = (const float*)d_in[0];
  const float* Y = (const float*)d_in[1];
  float* out  = (float*)d_out;
  float* cost = out;
  float* pi   = out + 1;

  char*  ws   = (char*)d_ws;
  float* x2   = (float*)ws;
  float* y2   = x2 + Nn;
  float* u    = y2 + Mm;
  float* v    = u + Mm;
  float* part = v + Nn;                                   // 128 x 8192 f32 = 4 MB
  const size_t small_bytes = (size_t)(4 * 8192 + 128 * 8192) * sizeof(float);
  const size_t e_off = (small_bytes + 255) & ~(size_t)255;
  const bool fast = ws_size >= e_off + (size_t)Nn * Mm * sizeof(h16) + 256;

  // fp16 X/Y copies parked inside the (not-yet-written) pi output region
  h16* Xh = (h16*)(((uintptr_t)pi + 15) & ~(uintptr_t)15);
  h16* Yh = Xh + (size_t)Nn * Kd;

  setup_kernel<<<4096, 256, 0, stream>>>(X, Y, x2, y2, u, cost, Xh, Yh);

  if (fast) {
    h16* E = (h16*)(ws + e_off);                          // fp16 K in workspace (128 MB, L3-resident)
    build_e_mfma<<<dim3(64, 64), 256, 0, stream>>>(Xh, Yh, x2, y2, E);
    for (int it = 0; it < 50; ++it) {
      row_pass_kernel<h16><<<2048, 256, 0, stream>>>(E, u, v);
      col_pass_kernel<h16><<<dim3(4, 128), 256, 0, stream>>>(E, v, part);
      combine_kernel<<<32, 256, 0, stream>>>(part, u);
    }
    final_pass_kernel<h16><<<2048, 256, 0, stream>>>(E, v, u, pi, cost);
  } else {
    float* E = pi;                                        // fallback: fp32 K parked in pi slot
    build_e_f32<float><<<dim3(128, 128), 256, 0, stream>>>(X, Y, x2, y2, E);
    for (int it = 0; it < 50; ++it) {
      row_pass_kernel<float><<<2048, 256, 0, stream>>>(E, u, v);
      col_pass_kernel<float><<<dim3(4, 128), 256, 0, stream>>>(E, v, part);
      combine_kernel<<<32, 256, 0, stream>>>(part, u);
    }
    final_pass_kernel<float><<<2048, 256, 0, stream>>>(E, v, u, pi, cost);  // in-place
  }
}